// Round 14
// baseline (133.286 us; speedup 1.0000x reference)
//
#include <hip/hip_runtime.h>

#define L2E 1.44269504088896340736f   // log2(e)
#define LN2 0.69314718055994530942f

// Raw HW transcendentals: v_exp_f32 = 2^x, v_log_f32 = log2(x).
#define EXP2F(x) __builtin_amdgcn_exp2f(x)
#define LOG2F(x) __builtin_amdgcn_logf(x)

// TWO independent batches per wave (b and b+256), 256 blocks x 64 threads.
// Rationale (R13 post-mortem): the per-CU L1 lookup pipe (~128 divergent
// line-lookups/step/CU) is the limiter, not per-wave latency. One wave per
// CU running two interleaved DPs retires 2 diagonals per stall-period at
// the same per-CU lookup rate. Each batch uses the proven R11 structure:
// branchless body, clamped unconditional loads, 8-deep ping-pong slots
// (xa/xb), g4 conversion 8 steps after load, 1 shfl/step, w-domain math
// (w = 2^(sig-E), w_new = g*(wa+wb+wc), g = 2^(-C*l2e), BIG == 0),
// block-floating renorm every 64 diagonals (exact 2^-e, sig -= e).

template <int I> __device__ __forceinline__ float comp(const float4& v) {
    if constexpr (I == 0) return v.x;
    else if constexpr (I == 1) return v.y;
    else if constexpr (I == 2) return v.z;
    else return v.w;
}

__device__ __forceinline__ float4 g4f(const float4& v) {
    float4 r;
    r.x = EXP2F(v.x * -L2E); r.y = EXP2F(v.y * -L2E);
    r.z = EXP2F(v.z * -L2E); r.w = EXP2F(v.w * -L2E);
    return r;
}

template <int P, int SB>
__device__ __forceinline__ void stepf(
    int kk, int t, int t4, const float* __restrict__ Cb,
    int rb0, int rb1, int rb2, int rb3,
    float4& c0, float4& c1, float4& c2, float4& c3,
    float4& n0, float4& n1, float4& n2, float4& n3,
    float4& xa0, float4& xa1, float4& xa2, float4& xa3,
    float4& xb0, float4& xb1, float4& xb2, float4& xb3,
    float& w10, float& w11, float& w12, float& w13,
    float& w20, float& w21, float& w22, float& w23,
    float& pd1, float& pd2)
{
    const int colr = kk + (12 - P) - t4;
    const int col  = colr < 0 ? 0 : (colr > 252 ? 252 : colr);
    const int rb   = (P == 0) ? rb0 : (P == 1) ? rb1 : (P == 2) ? rb2 : rb3;
    const float4 ld = *(const float4*)(Cb + rb + col);   // unconditional

    float4& cP = (P == 0) ? c0 : (P == 1) ? c1 : (P == 2) ? c2 : c3;
    float4& nP = (P == 0) ? n0 : (P == 1) ? n1 : (P == 2) ? n2 : n3;
    float4& sP = SB ? ((P == 0) ? xb0 : (P == 1) ? xb1 : (P == 2) ? xb2 : xb3)
                    : ((P == 0) ? xa0 : (P == 1) ? xa1 : (P == 2) ? xa2 : xa3);

    // convert the slot loaded 8 steps ago; zero it if it was past-the-end
    const bool junk = (colr > 260);
    float4 gq;
    gq.x = junk ? 0.0f : EXP2F(sP.x * -L2E);
    gq.y = junk ? 0.0f : EXP2F(sP.y * -L2E);
    gq.z = junk ? 0.0f : EXP2F(sP.z * -L2E);
    gq.w = junk ? 0.0f : EXP2F(sP.w * -L2E);
    cP = nP;
    nP = gq;
    sP = ld;

    const float g0 = comp<(P    ) & 3>(c0);
    const float g1 = comp<(P + 3) & 3>(c1);
    const float g2 = comp<(P + 2) & 3>(c2);
    const float g3 = comp<(P + 1) & 3>(c3);

    const float e0 = g0 * (w10 + pd1 + pd2);
    const float e1 = g1 * (w11 + w10 + w20);
    const float e2 = g2 * (w12 + w11 + w21);
    const float e3 = g3 * (w13 + w12 + w22);

    w20 = w10; w21 = w11; w22 = w12; w23 = w13;
    w10 = e0;  w11 = e1;  w12 = e2;  w13 = e3;

    const float nx = __shfl_up(e3, 1);
    pd2 = pd1;
    pd1 = (t == 0) ? 0.0f : nx;
}

__global__ __launch_bounds__(64, 1) void dp_softmin_wave(const float* __restrict__ C,
                                                         float* __restrict__ out) {
    const int b = blockIdx.x;
    const int t = threadIdx.x;
    const float* CbA = C + ((size_t)b << 16);
    const float* CbB = C + (((size_t)b + 256) << 16);
    const int t4 = 4 * t;

    const int rb0 = (t4 + 0) << 8;
    const int rb1 = (t4 + 1) << 8;
    const int rb2 = (t4 + 2) << 8;
    const int rb3 = (t4 + 3) << 8;

    auto cl = [](int c) { return c < 0 ? 0 : (c > 252 ? 252 : c); };
    auto q4 = [](const float* base, int rb, int col) {
        return *(const float4*)(base + rb + col);
    };

    // ---- batch A state (init = unconditional-machine fixed point, R11) ----
    float4 Ac0 = g4f(q4(CbA, rb0, 0)), Ac1 = g4f(q4(CbA, rb1, 0)),
           Ac2 = g4f(q4(CbA, rb2, 0)), Ac3 = g4f(q4(CbA, rb3, 0));
    float4 An0 = g4f(q4(CbA, rb0, cl(4 - t4)));
    float4 An1 = Ac1, An2 = Ac2, An3 = Ac3;
    float4 Axa0 = q4(CbA, rb0, cl(12 - t4));
    float4 Axa1 = q4(CbA, rb1, cl(4 - t4));
    float4 Axa2 = q4(CbA, rb2, cl(4 - t4));
    float4 Axa3 = q4(CbA, rb3, cl(4 - t4));
    float4 Axb0 = q4(CbA, rb0, cl(8 - t4)), Axb1 = q4(CbA, rb1, cl(8 - t4));
    float4 Axb2 = q4(CbA, rb2, cl(8 - t4)), Axb3 = q4(CbA, rb3, cl(8 - t4));
    float Aw10 = 0.0f, Aw11 = 0.0f, Aw12 = 0.0f, Aw13 = 0.0f;
    float Aw20 = 0.0f, Aw21 = 0.0f, Aw22 = 0.0f, Aw23 = 0.0f;
    float Apd1 = 0.0f, Apd2 = 0.0f;
    int sigA = 0;
    if (t == 0) Aw10 = Ac0.x;

    // ---- batch B state ----
    float4 Bc0 = g4f(q4(CbB, rb0, 0)), Bc1 = g4f(q4(CbB, rb1, 0)),
           Bc2 = g4f(q4(CbB, rb2, 0)), Bc3 = g4f(q4(CbB, rb3, 0));
    float4 Bn0 = g4f(q4(CbB, rb0, cl(4 - t4)));
    float4 Bn1 = Bc1, Bn2 = Bc2, Bn3 = Bc3;
    float4 Bxa0 = q4(CbB, rb0, cl(12 - t4));
    float4 Bxa1 = q4(CbB, rb1, cl(4 - t4));
    float4 Bxa2 = q4(CbB, rb2, cl(4 - t4));
    float4 Bxa3 = q4(CbB, rb3, cl(4 - t4));
    float4 Bxb0 = q4(CbB, rb0, cl(8 - t4)), Bxb1 = q4(CbB, rb1, cl(8 - t4));
    float4 Bxb2 = q4(CbB, rb2, cl(8 - t4)), Bxb3 = q4(CbB, rb3, cl(8 - t4));
    float Bw10 = 0.0f, Bw11 = 0.0f, Bw12 = 0.0f, Bw13 = 0.0f;
    float Bw20 = 0.0f, Bw21 = 0.0f, Bw22 = 0.0f, Bw23 = 0.0f;
    float Bpd1 = 0.0f, Bpd2 = 0.0f;
    int sigB = 0;
    if (t == 0) Bw10 = Bc0.x;

#define ARGS_A t, t4, CbA, rb0, rb1, rb2, rb3, Ac0,Ac1,Ac2,Ac3, An0,An1,An2,An3, \
               Axa0,Axa1,Axa2,Axa3, Axb0,Axb1,Axb2,Axb3, \
               Aw10,Aw11,Aw12,Aw13, Aw20,Aw21,Aw22,Aw23, Apd1,Apd2
#define ARGS_B t, t4, CbB, rb0, rb1, rb2, rb3, Bc0,Bc1,Bc2,Bc3, Bn0,Bn1,Bn2,Bn3, \
               Bxa0,Bxa1,Bxa2,Bxa3, Bxb0,Bxb1,Bxb2,Bxb3, \
               Bw10,Bw11,Bw12,Bw13, Bw20,Bw21,Bw22,Bw23, Bpd1,Bpd2
#define STEP2(kk, P, SB) do { stepf<P,SB>(kk, ARGS_A); stepf<P,SB>(kk, ARGS_B); } while (0)

    // prologue kk = 1..7
    STEP2(1, 1, 0); STEP2(2, 2, 0); STEP2(3, 3, 0);
    STEP2(4, 0, 1); STEP2(5, 1, 1); STEP2(6, 2, 1); STEP2(7, 3, 1);

#pragma clang loop unroll(disable)
    for (int kb = 8; kb <= 496; kb += 8) {
        if ((kb & 63) == 0) {
            // block-floating renorm both batches: exact 2^-e, sig -= e
            float MA = fmaxf(fmaxf(fmaxf(Aw10, Aw11), fmaxf(Aw12, Aw13)),
                             fmaxf(fmaxf(Aw20, Aw21), fmaxf(Aw22, Aw23)));
            float MB = fmaxf(fmaxf(fmaxf(Bw10, Bw11), fmaxf(Bw12, Bw13)),
                             fmaxf(fmaxf(Bw20, Bw21), fmaxf(Bw22, Bw23)));
            #pragma unroll
            for (int m = 1; m < 64; m <<= 1) {
                MA = fmaxf(MA, __shfl_xor(MA, m));
                MB = fmaxf(MB, __shfl_xor(MB, m));
            }
            int eA = ((__float_as_int(MA) >> 23) & 255) - 127;
            int eB = ((__float_as_int(MB) >> 23) & 255) - 127;
            float fA = __int_as_float((127 - eA) << 23);
            float fB = __int_as_float((127 - eB) << 23);
            Aw10 *= fA; Aw11 *= fA; Aw12 *= fA; Aw13 *= fA;
            Aw20 *= fA; Aw21 *= fA; Aw22 *= fA; Aw23 *= fA;
            Apd1 *= fA; Apd2 *= fA; sigA -= eA;
            Bw10 *= fB; Bw11 *= fB; Bw12 *= fB; Bw13 *= fB;
            Bw20 *= fB; Bw21 *= fB; Bw22 *= fB; Bw23 *= fB;
            Bpd1 *= fB; Bpd2 *= fB; sigB -= eB;
        }
        STEP2(kb + 0, 0, 0); STEP2(kb + 1, 1, 0);
        STEP2(kb + 2, 2, 0); STEP2(kb + 3, 3, 0);
        STEP2(kb + 4, 0, 1); STEP2(kb + 5, 1, 1);
        STEP2(kb + 6, 2, 1); STEP2(kb + 7, 3, 1);
    }

    // epilogue kk = 504..510
    STEP2(504, 0, 0); STEP2(505, 1, 0); STEP2(506, 2, 0); STEP2(507, 3, 0);
    STEP2(508, 0, 1); STEP2(509, 1, 1); STEP2(510, 2, 1);

#undef STEP2
#undef ARGS_A
#undef ARGS_B

    // corner cells (255,255): lane 63, E = sig - log2(w13), D = E * ln2
    if (t == 63) {
        out[b]       = ((float)sigA - LOG2F(Aw13)) * LN2;
        out[b + 256] = ((float)sigB - LOG2F(Bw13)) * LN2;
    }
}

extern "C" void kernel_launch(void* const* d_in, const int* in_sizes, int n_in,
                              void* d_out, int out_size, void* d_ws, size_t ws_size,
                              hipStream_t stream) {
    const float* C = (const float*)d_in[0];
    float* out = (float*)d_out;
    dp_softmin_wave<<<256, 64, 0, stream>>>(C, out);
}

// Round 17
// 67.584 us; speedup vs baseline: 1.9722x; 1.9722x over previous
//
#include <hip/hip_runtime.h>

#define S 256
#define L2E 1.44269504088896340736f   // log2(e)
#define LN2 0.69314718055994530942f

// Raw HW transcendentals: v_exp_f32 = 2^x, v_log_f32 = log2(x).
#define EXP2F(x) __builtin_amdgcn_exp2f(x)
#define LOG2F(x) __builtin_amdgcn_logf(x)

// Probability-domain soft-min DP, fully branchless body, 16-deep load pipe.
// R12 machine verbatim (verified correct, 68.5us) + ONE addition: an empty
// memory-clobber asm at each step boundary.  Rationale (R12-R16 post-mortem):
// LLVM register-sank the pipelined loads (R12 VGPR=80 < live state ~110),
// collapsing the software pipeline to depth ~1 and exposing ~250cy of cache
// latency per step.  A load cannot legally move across an asm that may
// store (memory clobber), so the barrier pins each step's load into its
// step; the barrier itself emits NO instructions and forces NO wait (it
// doesn't read the loaded values).  First use of a load is its conversion
// 16 steps later -> compiler's waitcnt pass emits counted vmcnt(~15) there.
// All loads/waits remain compiler-generated (no inline-asm load crashes).

template <int I> __device__ __forceinline__ float comp(const float4& v) {
    if constexpr (I == 0) return v.x;
    else if constexpr (I == 1) return v.y;
    else if constexpr (I == 2) return v.z;
    else return v.w;
}

__device__ __forceinline__ float4 g4f(const float4& v) {
    float4 r;
    r.x = EXP2F(v.x * -L2E); r.y = EXP2F(v.y * -L2E);
    r.z = EXP2F(v.z * -L2E); r.w = EXP2F(v.w * -L2E);
    return r;
}

template <int P, int SB>
__device__ __forceinline__ void stepf(
    int kk, int t, int t4, const float* __restrict__ Cb,
    int rb0, int rb1, int rb2, int rb3,
    float4& c0, float4& c1, float4& c2, float4& c3,
    float4& n0, float4& n1, float4& n2, float4& n3,
    float4& s00, float4& s01, float4& s02, float4& s03,
    float4& s10, float4& s11, float4& s12, float4& s13,
    float4& s20, float4& s21, float4& s22, float4& s23,
    float4& s30, float4& s31, float4& s32, float4& s33,
    float& w10, float& w11, float& w12, float& w13,
    float& w20, float& w21, float& w22, float& w23,
    float& pd1, float& pd2)
{
    const int colr = kk + (20 - P) - t4;
    const int col  = colr < 0 ? 0 : (colr > 252 ? 252 : colr);
    const int rb   = (P == 0) ? rb0 : (P == 1) ? rb1 : (P == 2) ? rb2 : rb3;
    const float4 ld = *(const float4*)(Cb + rb + col);   // unconditional

    float4& cP = (P == 0) ? c0 : (P == 1) ? c1 : (P == 2) ? c2 : c3;
    float4& nP = (P == 0) ? n0 : (P == 1) ? n1 : (P == 2) ? n2 : n3;
    float4& sP =
        (SB == 0) ? ((P == 0) ? s00 : (P == 1) ? s01 : (P == 2) ? s02 : s03)
      : (SB == 1) ? ((P == 0) ? s10 : (P == 1) ? s11 : (P == 2) ? s12 : s13)
      : (SB == 2) ? ((P == 0) ? s20 : (P == 1) ? s21 : (P == 2) ? s22 : s23)
                  : ((P == 0) ? s30 : (P == 1) ? s31 : (P == 2) ? s32 : s33);

    // convert the slot loaded 16 steps ago; zero it if it was past-the-end
    const bool junk = (colr > 268);
    float4 gq;
    gq.x = junk ? 0.0f : EXP2F(sP.x * -L2E);
    gq.y = junk ? 0.0f : EXP2F(sP.y * -L2E);
    gq.z = junk ? 0.0f : EXP2F(sP.z * -L2E);
    gq.w = junk ? 0.0f : EXP2F(sP.w * -L2E);
    cP = nP;
    nP = gq;
    sP = ld;

    const float g0 = comp<(P    ) & 3>(c0);
    const float g1 = comp<(P + 3) & 3>(c1);
    const float g2 = comp<(P + 2) & 3>(c2);
    const float g3 = comp<(P + 1) & 3>(c3);

    const float e0 = g0 * (w10 + pd1 + pd2);
    const float e1 = g1 * (w11 + w10 + w20);
    const float e2 = g2 * (w12 + w11 + w21);
    const float e3 = g3 * (w13 + w12 + w22);

    w20 = w10; w21 = w11; w22 = w12; w23 = w13;
    w10 = e0;  w11 = e1;  w12 = e2;  w13 = e3;

    const float nx = __shfl_up(e3, 1);
    pd2 = pd1;
    pd1 = (t == 0) ? 0.0f : nx;

    // step boundary: loads cannot sink across a may-store asm -> the 16-deep
    // issue schedule is pinned.  Emits no instructions, forces no waitcnt.
    asm volatile("" ::: "memory");
}

__global__ __launch_bounds__(64, 1) void dp_softmin_wave(const float* __restrict__ C,
                                                         float* __restrict__ out) {
    const int b = blockIdx.x;
    const int t = threadIdx.x;
    const float* Cb = C + ((size_t)b << 16);
    const int t4 = 4 * t;

    const int rb0 = (t4 + 0) << 8;
    const int rb1 = (t4 + 1) << 8;
    const int rb2 = (t4 + 2) << 8;
    const int rb3 = (t4 + 3) << 8;

    auto cl = [](int c) { return c < 0 ? 0 : (c > 252 ? 252 : c); };
    auto q4 = [&](int rb, int col) { return *(const float4*)(Cb + rb + col); };

    // init = fixed point of the unconditional machine for kk <= 0 (R12)
    float4 c0 = g4f(q4(rb0, 0)), c1 = g4f(q4(rb1, 0)),
           c2 = g4f(q4(rb2, 0)), c3 = g4f(q4(rb3, 0));
    float4 n0 = g4f(q4(rb0, cl(4 - t4)));
    float4 n1 = c1, n2 = c2, n3 = c3;

    float4 s00 = q4(rb0, cl(20 - t4));
    float4 s01 = q4(rb1, cl(4 - t4));
    float4 s02 = q4(rb2, cl(4 - t4));
    float4 s03 = q4(rb3, cl(4 - t4));
    float4 s10 = q4(rb0, cl(8 - t4)),  s11 = q4(rb1, cl(8 - t4));
    float4 s12 = q4(rb2, cl(8 - t4)),  s13 = q4(rb3, cl(8 - t4));
    float4 s20 = q4(rb0, cl(12 - t4)), s21 = q4(rb1, cl(12 - t4));
    float4 s22 = q4(rb2, cl(12 - t4)), s23 = q4(rb3, cl(12 - t4));
    float4 s30 = q4(rb0, cl(16 - t4)), s31 = q4(rb1, cl(16 - t4));
    float4 s32 = q4(rb2, cl(16 - t4)), s33 = q4(rb3, cl(16 - t4));

    float w10 = 0.0f, w11 = 0.0f, w12 = 0.0f, w13 = 0.0f;
    float w20 = 0.0f, w21 = 0.0f, w22 = 0.0f, w23 = 0.0f;
    float pd1 = 0.0f, pd2 = 0.0f;
    int sig = 0;

    if (t == 0) w10 = c0.x;                // seed: w(0,0) = g(0,0)

    asm volatile("" ::: "memory");          // pin init loads above the chain

#define ARGS t, t4, Cb, rb0, rb1, rb2, rb3, c0,c1,c2,c3, n0,n1,n2,n3, \
             s00,s01,s02,s03, s10,s11,s12,s13, s20,s21,s22,s23, s30,s31,s32,s33, \
             w10,w11,w12,w13, w20,w21,w22,w23, pd1,pd2

    // prologue kk = 1..15
    stepf<1,0>(1, ARGS);  stepf<2,0>(2, ARGS);  stepf<3,0>(3, ARGS);
    stepf<0,1>(4, ARGS);  stepf<1,1>(5, ARGS);  stepf<2,1>(6, ARGS);  stepf<3,1>(7, ARGS);
    stepf<0,2>(8, ARGS);  stepf<1,2>(9, ARGS);  stepf<2,2>(10, ARGS); stepf<3,2>(11, ARGS);
    stepf<0,3>(12, ARGS); stepf<1,3>(13, ARGS); stepf<2,3>(14, ARGS); stepf<3,3>(15, ARGS);

#pragma clang loop unroll(disable)
    for (int kb = 16; kb <= 480; kb += 16) {
        if ((kb & 63) == 0) {
            // block-floating renorm: exact power-of-2, sig -= e
            float M = fmaxf(fmaxf(fmaxf(w10, w11), fmaxf(w12, w13)),
                            fmaxf(fmaxf(w20, w21), fmaxf(w22, w23)));
            #pragma unroll
            for (int m = 1; m < 64; m <<= 1) M = fmaxf(M, __shfl_xor(M, m));
            int e = ((__float_as_int(M) >> 23) & 255) - 127;
            float f = __int_as_float((127 - e) << 23);
            w10 *= f; w11 *= f; w12 *= f; w13 *= f;
            w20 *= f; w21 *= f; w22 *= f; w23 *= f;
            pd1 *= f; pd2 *= f;
            sig -= e;
        }
        stepf<0,0>(kb + 0, ARGS);  stepf<1,0>(kb + 1, ARGS);
        stepf<2,0>(kb + 2, ARGS);  stepf<3,0>(kb + 3, ARGS);
        stepf<0,1>(kb + 4, ARGS);  stepf<1,1>(kb + 5, ARGS);
        stepf<2,1>(kb + 6, ARGS);  stepf<3,1>(kb + 7, ARGS);
        stepf<0,2>(kb + 8, ARGS);  stepf<1,2>(kb + 9, ARGS);
        stepf<2,2>(kb + 10, ARGS); stepf<3,2>(kb + 11, ARGS);
        stepf<0,3>(kb + 12, ARGS); stepf<1,3>(kb + 13, ARGS);
        stepf<2,3>(kb + 14, ARGS); stepf<3,3>(kb + 15, ARGS);
    }

    // epilogue kk = 496..510
    stepf<0,0>(496, ARGS); stepf<1,0>(497, ARGS); stepf<2,0>(498, ARGS); stepf<3,0>(499, ARGS);
    stepf<0,1>(500, ARGS); stepf<1,1>(501, ARGS); stepf<2,1>(502, ARGS); stepf<3,1>(503, ARGS);
    stepf<0,2>(504, ARGS); stepf<1,2>(505, ARGS); stepf<2,2>(506, ARGS); stepf<3,2>(507, ARGS);
    stepf<0,3>(508, ARGS); stepf<1,3>(509, ARGS); stepf<2,3>(510, ARGS);
#undef ARGS

    // corner cell (255,255): lane 63, E = sig - log2(w13), D = E * ln2
    if (t == 63) out[b] = ((float)sig - LOG2F(w13)) * LN2;
}

extern "C" void kernel_launch(void* const* d_in, const int* in_sizes, int n_in,
                              void* d_out, int out_size, void* d_ws, size_t ws_size,
                              hipStream_t stream) {
    const float* C = (const float*)d_in[0];
    float* out = (float*)d_out;
    dp_softmin_wave<<<512, 64, 0, stream>>>(C, out);
}